// Round 1
// baseline (250.533 us; speedup 1.0000x reference)
//
#include <hip/hip_runtime.h>
#include <math.h>

#define LN_ZERO (-100000000000.0f)

constexpr int F_ = 250000;
constexpr int D_ = 4;
constexpr int C_ = 2;
constexpr int V_ = 250000;
constexpr int E_ = F_ * D_;      // 1,000,000
constexpr int CD_ = 16;          // C^D

// ---------------------------------------------------------------------------
// K1: accumulate prv messages into vb_prv (raw sums, clamp applied at read)
__global__ void k_accum_vb_prv(const float2* __restrict__ msgs,
                               const int* __restrict__ edge_v,
                               float* __restrict__ vb) {
    int e = blockIdx.x * blockDim.x + threadIdx.x;
    if (e >= E_) return;
    float2 m = msgs[e];
    int v = edge_v[e];
    atomicAdd(&vb[2 * v + 0], m.x);
    atomicAdd(&vb[2 * v + 1], m.y);
}

// ---------------------------------------------------------------------------
// K2: v2f_prv[e,c] = clamp(clamp(vb_prv)[v,c] - msgs[e,c])
__global__ void k_v2f_prv(const float2* __restrict__ msgs,
                          const int* __restrict__ edge_v,
                          const float* __restrict__ vb,
                          const unsigned char* __restrict__ vb_mask,
                          const unsigned char* __restrict__ v2f_mask,
                          float2* __restrict__ v2f) {
    int e = blockIdx.x * blockDim.x + threadIdx.x;
    if (e >= E_) return;
    int v = edge_v[e];
    float b0 = vb[2 * v + 0];
    float b1 = vb[2 * v + 1];
    b0 = fmaxf(vb_mask[2 * v + 0] ? LN_ZERO : b0, LN_ZERO);
    b1 = fmaxf(vb_mask[2 * v + 1] ? LN_ZERO : b1, LN_ZERO);
    float2 m = msgs[e];
    float t0 = b0 - m.x;
    float t1 = b1 - m.y;
    t0 = fmaxf(v2f_mask[2 * e + 0] ? LN_ZERO : t0, LN_ZERO);
    t1 = fmaxf(v2f_mask[2 * e + 1] ? LN_ZERO : t1, LN_ZERO);
    v2f[e] = make_float2(t0, t1);
}

// ---------------------------------------------------------------------------
// K3: per factor — factor belief, max-marginalize, normalize -> new_f2v.
// Also fuses phase-2 vb accumulation (atomicAdd of new_f2v into out_vb).
__global__ void k_factor_msgs(const float2* __restrict__ v2f,
                              const float4* __restrict__ pot4,
                              const int4* __restrict__ potmask4,
                              const unsigned char* __restrict__ f2v_mask,
                              const int* __restrict__ edge_v,
                              float2* __restrict__ out_f2v,
                              float* __restrict__ out_vb) {
    int f = blockIdx.x * blockDim.x + threadIdx.x;
    if (f >= F_) return;

    float2 w[4];
#pragma unroll
    for (int d = 0; d < 4; ++d) w[d] = v2f[4 * f + d];

    float fb[16];
#pragma unroll
    for (int j = 0; j < 4; ++j) {
        float4 p = pot4[4 * f + j];
        int4 pm = potmask4[4 * f + j];
        float base[4] = {p.x, p.y, p.z, p.w};
        int   mb[4]   = {pm.x, pm.y, pm.z, pm.w};
#pragma unroll
        for (int k = 0; k < 4; ++k) {
            int s = 4 * j + k;
            float acc = base[k];
#pragma unroll
            for (int d = 0; d < 4; ++d) {
                int bit = (s >> (3 - d)) & 1;
                acc += bit ? w[d].y : w[d].x;
            }
            fb[s] = fmaxf(mb[k] == 1 ? LN_ZERO : acc, LN_ZERO);
        }
    }

    // max-marginals: mm[d][c] = max over states s with bit_d(s)==c of fb[s]
    float mm[4][2];
#pragma unroll
    for (int d = 0; d < 4; ++d) { mm[d][0] = -INFINITY; mm[d][1] = -INFINITY; }
#pragma unroll
    for (int s = 0; s < 16; ++s) {
        float v = fb[s];
#pragma unroll
        for (int d = 0; d < 4; ++d) {
            int bit = (s >> (3 - d)) & 1;
            mm[d][bit] = fmaxf(mm[d][bit], v);
        }
    }

#pragma unroll
    for (int d = 0; d < 4; ++d) {
        int e = 4 * f + d;
        float raw0 = mm[d][0] - w[d].x;
        float raw1 = mm[d][1] - w[d].y;
        // stable logsumexp over the 2 states
        float mx = fmaxf(raw0, raw1);
        float lse = mx + logf(expf(raw0 - mx) + expf(raw1 - mx));
        float o0 = raw0 - lse;
        float o1 = raw1 - lse;
        o0 = fmaxf(f2v_mask[2 * e + 0] ? LN_ZERO : o0, LN_ZERO);
        o1 = fmaxf(f2v_mask[2 * e + 1] ? LN_ZERO : o1, LN_ZERO);
        out_f2v[e] = make_float2(o0, o1);
        int v = edge_v[e];
        atomicAdd(&out_vb[2 * v + 0], o0);
        atomicAdd(&out_vb[2 * v + 1], o1);
    }
}

// ---------------------------------------------------------------------------
// K4: clamp vb_new in place (this is the vb output)
__global__ void k_clamp_vb(float* __restrict__ vb,
                           const unsigned char* __restrict__ vb_mask) {
    int i = blockIdx.x * blockDim.x + threadIdx.x;
    if (i >= V_ * C_) return;
    float x = vb[i];
    x = fmaxf(vb_mask[i] ? LN_ZERO : x, LN_ZERO);
    vb[i] = x;
}

// ---------------------------------------------------------------------------
// K5: per factor — recompute v2f_new on the fly, fb_new = sum + pot (output)
__global__ void k_factor_beliefs(const float2* __restrict__ new_f2v,
                                 const float* __restrict__ vb,       // clamped
                                 const int* __restrict__ edge_v,
                                 const float4* __restrict__ pot4,
                                 const int4* __restrict__ potmask4,
                                 const unsigned char* __restrict__ v2f_mask,
                                 float4* __restrict__ out_fb4) {
    int f = blockIdx.x * blockDim.x + threadIdx.x;
    if (f >= F_) return;

    float2 w[4];
#pragma unroll
    for (int d = 0; d < 4; ++d) {
        int e = 4 * f + d;
        int v = edge_v[e];
        float b0 = vb[2 * v + 0];
        float b1 = vb[2 * v + 1];
        float2 g = new_f2v[e];
        float t0 = b0 - g.x;
        float t1 = b1 - g.y;
        t0 = fmaxf(v2f_mask[2 * e + 0] ? LN_ZERO : t0, LN_ZERO);
        t1 = fmaxf(v2f_mask[2 * e + 1] ? LN_ZERO : t1, LN_ZERO);
        w[d] = make_float2(t0, t1);
    }

#pragma unroll
    for (int j = 0; j < 4; ++j) {
        float4 p = pot4[4 * f + j];
        int4 pm = potmask4[4 * f + j];
        float base[4] = {p.x, p.y, p.z, p.w};
        int   mb[4]   = {pm.x, pm.y, pm.z, pm.w};
        float o[4];
#pragma unroll
        for (int k = 0; k < 4; ++k) {
            int s = 4 * j + k;
            float acc = base[k];
#pragma unroll
            for (int d = 0; d < 4; ++d) {
                int bit = (s >> (3 - d)) & 1;
                acc += bit ? w[d].y : w[d].x;
            }
            o[k] = fmaxf(mb[k] == 1 ? LN_ZERO : acc, LN_ZERO);
        }
        out_fb4[4 * f + j] = make_float4(o[0], o[1], o[2], o[3]);
    }
}

// ---------------------------------------------------------------------------
extern "C" void kernel_launch(void* const* d_in, const int* in_sizes, int n_in,
                              void* d_out, int out_size, void* d_ws, size_t ws_size,
                              hipStream_t stream) {
    const float* msgs        = (const float*)d_in[0];           // [E, C]
    const float* pot         = (const float*)d_in[1];           // [F, 16]
    const int*   edge_idx    = (const int*)d_in[2];             // [2, E]
    // d_in[3] (facStates_to_varIdx) and d_in[4] (scatter idx): analytic, unused
    const int*   pot_mask    = (const int*)d_in[5];             // [F, 16] int32
    const unsigned char* f2v_mask = (const unsigned char*)d_in[6];  // [E, C] bool
    const unsigned char* v2f_mask = (const unsigned char*)d_in[7];  // [E, C] bool
    const unsigned char* vb_mask  = (const unsigned char*)d_in[8];  // [V, C] bool

    const int* edge_v = edge_idx + E_;

    float* out      = (float*)d_out;
    float* out_f2v  = out;                      // E*C = 2,000,000
    float* out_vb   = out + E_ * C_;            // V*C =   500,000
    float* out_fb   = out_vb + V_ * C_;         // F*16 = 4,000,000

    float* ws_vb  = (float*)d_ws;               // V*C floats
    float* ws_v2f = ws_vb + V_ * C_;            // E*C floats

    hipMemsetAsync(ws_vb, 0, (size_t)V_ * C_ * sizeof(float), stream);
    hipMemsetAsync(out_vb, 0, (size_t)V_ * C_ * sizeof(float), stream);

    const int B = 256;
    dim3 gE((E_ + B - 1) / B), gF((F_ + B - 1) / B), gV((V_ * C_ + B - 1) / B);

    k_accum_vb_prv<<<gE, B, 0, stream>>>((const float2*)msgs, edge_v, ws_vb);
    k_v2f_prv<<<gE, B, 0, stream>>>((const float2*)msgs, edge_v, ws_vb,
                                    vb_mask, v2f_mask, (float2*)ws_v2f);
    k_factor_msgs<<<gF, B, 0, stream>>>((const float2*)ws_v2f,
                                        (const float4*)pot, (const int4*)pot_mask,
                                        f2v_mask, edge_v,
                                        (float2*)out_f2v, out_vb);
    k_clamp_vb<<<gV, B, 0, stream>>>(out_vb, vb_mask);
    k_factor_beliefs<<<gF, B, 0, stream>>>((const float2*)out_f2v, out_vb, edge_v,
                                           (const float4*)pot, (const int4*)pot_mask,
                                           v2f_mask, (float4*)out_fb);
}

// Round 2
// 165.686 us; speedup vs baseline: 1.5121x; 1.5121x over previous
//
#include <hip/hip_runtime.h>
#include <math.h>

#define LN_ZERO (-100000000000.0f)

constexpr int F_ = 250000;
constexpr int C_ = 2;
constexpr int V_ = 250000;
constexpr int E_ = 1000000;      // F_ * 4
constexpr int SCAN_B = 1024;
constexpr int NB_SCAN = (V_ + SCAN_B - 1) / SCAN_B;   // 245
static_assert(NB_SCAN <= 256, "top-level scan assumes <=256 partials");

// ---------------------------------------------------------------------------
// CSR build step 1: count[v]++ and remember each edge's slot within its var.
__global__ void k_slot(const int* __restrict__ edge_v,
                       int* __restrict__ count,
                       int* __restrict__ slot) {
    int e = blockIdx.x * blockDim.x + threadIdx.x;
    if (e >= E_) return;
    slot[e] = atomicAdd(&count[edge_v[e]], 1);
}

// CSR build step 2a: per-block sums of count
__global__ void k_scan_blocksum(const int* __restrict__ count,
                                int* __restrict__ sums) {
    __shared__ int sm[SCAN_B];
    int tid = threadIdx.x;
    int i = blockIdx.x * SCAN_B + tid;
    sm[tid] = (i < V_) ? count[i] : 0;
    __syncthreads();
    for (int s = SCAN_B / 2; s > 0; s >>= 1) {
        if (tid < s) sm[tid] += sm[tid + s];
        __syncthreads();
    }
    if (tid == 0) sums[blockIdx.x] = sm[0];
}

// CSR build step 2b: exclusive scan of the block sums (single block)
__global__ void k_scan_top(const int* __restrict__ sums,
                           int* __restrict__ pre) {
    __shared__ int sm[256];
    int tid = threadIdx.x;
    int v = (tid < NB_SCAN) ? sums[tid] : 0;
    sm[tid] = v;
    __syncthreads();
    for (int off = 1; off < 256; off <<= 1) {
        int t = (tid >= off) ? sm[tid - off] : 0;
        __syncthreads();
        sm[tid] += t;
        __syncthreads();
    }
    if (tid < NB_SCAN) pre[tid] = sm[tid] - v;   // exclusive prefix
}

// CSR build step 2c: offsets[v] = global exclusive prefix of count
__global__ void k_scan_offsets(const int* __restrict__ count,
                               const int* __restrict__ pre,
                               int* __restrict__ offs) {
    __shared__ int sm[SCAN_B];
    int tid = threadIdx.x;
    int i = blockIdx.x * SCAN_B + tid;
    int c = (i < V_) ? count[i] : 0;
    sm[tid] = c;
    __syncthreads();
    for (int off = 1; off < SCAN_B; off <<= 1) {
        int t = (tid >= off) ? sm[tid - off] : 0;
        __syncthreads();
        sm[tid] += t;
        __syncthreads();
    }
    if (i < V_) offs[i] = pre[blockIdx.x] + sm[tid] - c;
}

// CSR build step 3: scatter edge ids into variable-ordered list (no atomics)
__global__ void k_place(const int* __restrict__ edge_v,
                        const int* __restrict__ slot,
                        const int* __restrict__ offs,
                        int* __restrict__ elist) {
    int e = blockIdx.x * blockDim.x + threadIdx.x;
    if (e >= E_) return;
    elist[offs[edge_v[e]] + slot[e]] = e;
}

// ---------------------------------------------------------------------------
// Phase 1: per variable — vb_prv = clamp(sum msgs), then v2f_prv per edge.
__global__ void k_vb_v2f_prv(const int* __restrict__ offs,
                             const int* __restrict__ count,
                             const int* __restrict__ elist,
                             const float2* __restrict__ msgs,
                             const unsigned char* __restrict__ vb_mask,
                             const unsigned char* __restrict__ v2f_mask,
                             float2* __restrict__ v2f) {
    int v = blockIdx.x * blockDim.x + threadIdx.x;
    if (v >= V_) return;
    int o = offs[v], n = count[v];
    float s0 = 0.f, s1 = 0.f;
    for (int i = 0; i < n; ++i) {
        float2 m = msgs[elist[o + i]];
        s0 += m.x; s1 += m.y;
    }
    float b0 = fmaxf(vb_mask[2 * v + 0] ? LN_ZERO : s0, LN_ZERO);
    float b1 = fmaxf(vb_mask[2 * v + 1] ? LN_ZERO : s1, LN_ZERO);
    for (int i = 0; i < n; ++i) {
        int e = elist[o + i];
        float2 m = msgs[e];
        float t0 = fmaxf(v2f_mask[2 * e + 0] ? LN_ZERO : (b0 - m.x), LN_ZERO);
        float t1 = fmaxf(v2f_mask[2 * e + 1] ? LN_ZERO : (b1 - m.y), LN_ZERO);
        v2f[e] = make_float2(t0, t1);
    }
}

// ---------------------------------------------------------------------------
// Per factor: factor belief, max-marginalize, normalize -> new_f2v (atomic-free)
__global__ void k_factor_msgs(const float2* __restrict__ v2f,
                              const float4* __restrict__ pot4,
                              const int4* __restrict__ potmask4,
                              const unsigned char* __restrict__ f2v_mask,
                              float2* __restrict__ out_f2v) {
    int f = blockIdx.x * blockDim.x + threadIdx.x;
    if (f >= F_) return;

    float2 w[4];
#pragma unroll
    for (int d = 0; d < 4; ++d) w[d] = v2f[4 * f + d];

    float fb[16];
#pragma unroll
    for (int j = 0; j < 4; ++j) {
        float4 p = pot4[4 * f + j];
        int4 pm = potmask4[4 * f + j];
        float base[4] = {p.x, p.y, p.z, p.w};
        int   mb[4]   = {pm.x, pm.y, pm.z, pm.w};
#pragma unroll
        for (int k = 0; k < 4; ++k) {
            int s = 4 * j + k;
            float acc = base[k];
#pragma unroll
            for (int d = 0; d < 4; ++d) {
                int bit = (s >> (3 - d)) & 1;
                acc += bit ? w[d].y : w[d].x;
            }
            fb[s] = fmaxf(mb[k] == 1 ? LN_ZERO : acc, LN_ZERO);
        }
    }

    float mm[4][2];
#pragma unroll
    for (int d = 0; d < 4; ++d) { mm[d][0] = -INFINITY; mm[d][1] = -INFINITY; }
#pragma unroll
    for (int s = 0; s < 16; ++s) {
        float v = fb[s];
#pragma unroll
        for (int d = 0; d < 4; ++d) {
            int bit = (s >> (3 - d)) & 1;
            mm[d][bit] = fmaxf(mm[d][bit], v);
        }
    }

#pragma unroll
    for (int d = 0; d < 4; ++d) {
        int e = 4 * f + d;
        float raw0 = mm[d][0] - w[d].x;
        float raw1 = mm[d][1] - w[d].y;
        float mx = fmaxf(raw0, raw1);
        float lse = mx + logf(expf(raw0 - mx) + expf(raw1 - mx));
        float o0 = raw0 - lse;
        float o1 = raw1 - lse;
        o0 = fmaxf(f2v_mask[2 * e + 0] ? LN_ZERO : o0, LN_ZERO);
        o1 = fmaxf(f2v_mask[2 * e + 1] ? LN_ZERO : o1, LN_ZERO);
        out_f2v[e] = make_float2(o0, o1);
    }
}

// ---------------------------------------------------------------------------
// Phase 2: per variable — vb_new = clamp(sum new_f2v) -> out_vb (clamped output)
__global__ void k_vb_new(const int* __restrict__ offs,
                         const int* __restrict__ count,
                         const int* __restrict__ elist,
                         const float2* __restrict__ f2v,
                         const unsigned char* __restrict__ vb_mask,
                         float2* __restrict__ out_vb) {
    int v = blockIdx.x * blockDim.x + threadIdx.x;
    if (v >= V_) return;
    int o = offs[v], n = count[v];
    float s0 = 0.f, s1 = 0.f;
    for (int i = 0; i < n; ++i) {
        float2 m = f2v[elist[o + i]];
        s0 += m.x; s1 += m.y;
    }
    float b0 = fmaxf(vb_mask[2 * v + 0] ? LN_ZERO : s0, LN_ZERO);
    float b1 = fmaxf(vb_mask[2 * v + 1] ? LN_ZERO : s1, LN_ZERO);
    out_vb[v] = make_float2(b0, b1);
}

// ---------------------------------------------------------------------------
// Per factor: recompute v2f_new on the fly, fb_new = sum + pot (output)
__global__ void k_factor_beliefs(const float2* __restrict__ new_f2v,
                                 const float* __restrict__ vb,       // clamped
                                 const int* __restrict__ edge_v,
                                 const float4* __restrict__ pot4,
                                 const int4* __restrict__ potmask4,
                                 const unsigned char* __restrict__ v2f_mask,
                                 float4* __restrict__ out_fb4) {
    int f = blockIdx.x * blockDim.x + threadIdx.x;
    if (f >= F_) return;

    float2 w[4];
#pragma unroll
    for (int d = 0; d < 4; ++d) {
        int e = 4 * f + d;
        int v = edge_v[e];
        float b0 = vb[2 * v + 0];
        float b1 = vb[2 * v + 1];
        float2 g = new_f2v[e];
        float t0 = fmaxf(v2f_mask[2 * e + 0] ? LN_ZERO : (b0 - g.x), LN_ZERO);
        float t1 = fmaxf(v2f_mask[2 * e + 1] ? LN_ZERO : (b1 - g.y), LN_ZERO);
        w[d] = make_float2(t0, t1);
    }

#pragma unroll
    for (int j = 0; j < 4; ++j) {
        float4 p = pot4[4 * f + j];
        int4 pm = potmask4[4 * f + j];
        float base[4] = {p.x, p.y, p.z, p.w};
        int   mb[4]   = {pm.x, pm.y, pm.z, pm.w};
        float o[4];
#pragma unroll
        for (int k = 0; k < 4; ++k) {
            int s = 4 * j + k;
            float acc = base[k];
#pragma unroll
            for (int d = 0; d < 4; ++d) {
                int bit = (s >> (3 - d)) & 1;
                acc += bit ? w[d].y : w[d].x;
            }
            o[k] = fmaxf(mb[k] == 1 ? LN_ZERO : acc, LN_ZERO);
        }
        out_fb4[4 * f + j] = make_float4(o[0], o[1], o[2], o[3]);
    }
}

// ---------------------------------------------------------------------------
extern "C" void kernel_launch(void* const* d_in, const int* in_sizes, int n_in,
                              void* d_out, int out_size, void* d_ws, size_t ws_size,
                              hipStream_t stream) {
    const float* msgs     = (const float*)d_in[0];           // [E, C]
    const float* pot      = (const float*)d_in[1];           // [F, 16]
    const int*   edge_idx = (const int*)d_in[2];             // [2, E]
    const int*   pot_mask = (const int*)d_in[5];             // [F, 16] int32
    const unsigned char* f2v_mask = (const unsigned char*)d_in[6];  // [E, C]
    const unsigned char* v2f_mask = (const unsigned char*)d_in[7];  // [E, C]
    const unsigned char* vb_mask  = (const unsigned char*)d_in[8];  // [V, C]

    const int* edge_v = edge_idx + E_;

    float* out      = (float*)d_out;
    float* out_f2v  = out;                          // E*C floats
    float* out_vb   = out + (size_t)E_ * C_;        // V*C floats
    float* out_fb   = out_vb + (size_t)V_ * C_;     // F*16 floats

    // workspace layout (ints): count[V] offs[V] elist[E] slot[E] sums/pre[512]
    // v2f (float2[E], 8 MB) reuses slot+sums region (dead after k_place/scan).
    int* ws_i  = (int*)d_ws;
    int* count = ws_i;                       // V
    int* offs  = ws_i + V_;                  // V
    int* elist = ws_i + 2 * V_;              // E
    int* slot  = ws_i + 2 * V_ + E_;         // E
    int* sums  = ws_i + 2 * V_ + 2 * E_;     // NB_SCAN
    int* pre   = sums + 256;                 // NB_SCAN
    float2* v2f = (float2*)(ws_i + 2 * V_ + E_);   // overlaps slot/sums/pre
    // total ws bytes needed: (2*V_ + 3*E_) * 4 = 14,000,000

    hipMemsetAsync(count, 0, (size_t)V_ * sizeof(int), stream);

    const int B = 256;
    dim3 gE((E_ + B - 1) / B), gF((F_ + B - 1) / B), gV((V_ + B - 1) / B);

    k_slot<<<gE, B, 0, stream>>>(edge_v, count, slot);
    k_scan_blocksum<<<NB_SCAN, SCAN_B, 0, stream>>>(count, sums);
    k_scan_top<<<1, 256, 0, stream>>>(sums, pre);
    k_scan_offsets<<<NB_SCAN, SCAN_B, 0, stream>>>(count, pre, offs);
    k_place<<<gE, B, 0, stream>>>(edge_v, slot, offs, elist);
    k_vb_v2f_prv<<<gV, B, 0, stream>>>(offs, count, elist, (const float2*)msgs,
                                       vb_mask, v2f_mask, v2f);
    k_factor_msgs<<<gF, B, 0, stream>>>(v2f, (const float4*)pot,
                                        (const int4*)pot_mask, f2v_mask,
                                        (float2*)out_f2v);
    k_vb_new<<<gV, B, 0, stream>>>(offs, count, elist, (const float2*)out_f2v,
                                   vb_mask, (float2*)out_vb);
    k_factor_beliefs<<<gF, B, 0, stream>>>((const float2*)out_f2v, out_vb, edge_v,
                                           (const float4*)pot, (const int4*)pot_mask,
                                           v2f_mask, (float4*)out_fb);
}

// Round 3
// 137.957 us; speedup vs baseline: 1.8160x; 1.2010x over previous
//
#include <hip/hip_runtime.h>
#include <math.h>

#define LN_ZERO (-100000000000.0f)

constexpr int F_ = 250000;
constexpr int V_ = 250000;
constexpr int E_ = 1000000;      // F_ * 4
constexpr int SCAN_B = 1024;
constexpr int NB_SCAN = (V_ + SCAN_B - 1) / SCAN_B;   // 245
static_assert(NB_SCAN <= 256, "top-level scan assumes <=256 partials");

// ---------------------------------------------------------------------------
// CSR build step 1: count[v]++ and remember each edge's slot within its var.
__global__ void k_slot(const int* __restrict__ edge_v,
                       int* __restrict__ count,
                       int* __restrict__ slot) {
    int e = blockIdx.x * blockDim.x + threadIdx.x;
    if (e >= E_) return;
    slot[e] = atomicAdd(&count[edge_v[e]], 1);
}

// CSR build step 2a: per-block sums of count
__global__ void k_scan_blocksum(const int* __restrict__ count,
                                int* __restrict__ sums) {
    __shared__ int sm[SCAN_B];
    int tid = threadIdx.x;
    int i = blockIdx.x * SCAN_B + tid;
    sm[tid] = (i < V_) ? count[i] : 0;
    __syncthreads();
    for (int s = SCAN_B / 2; s > 0; s >>= 1) {
        if (tid < s) sm[tid] += sm[tid + s];
        __syncthreads();
    }
    if (tid == 0) sums[blockIdx.x] = sm[0];
}

// CSR build step 2b: exclusive scan of the block sums (single block)
__global__ void k_scan_top(const int* __restrict__ sums,
                           int* __restrict__ pre) {
    __shared__ int sm[256];
    int tid = threadIdx.x;
    int v = (tid < NB_SCAN) ? sums[tid] : 0;
    sm[tid] = v;
    __syncthreads();
    for (int off = 1; off < 256; off <<= 1) {
        int t = (tid >= off) ? sm[tid - off] : 0;
        __syncthreads();
        sm[tid] += t;
        __syncthreads();
    }
    if (tid < NB_SCAN) pre[tid] = sm[tid] - v;   // exclusive prefix
}

// CSR build step 2c: offs[v] = global exclusive prefix of count
__global__ void k_scan_offsets(const int* __restrict__ count,
                               const int* __restrict__ pre,
                               int* __restrict__ offs) {
    __shared__ int sm[SCAN_B];
    int tid = threadIdx.x;
    int i = blockIdx.x * SCAN_B + tid;
    int c = (i < V_) ? count[i] : 0;
    sm[tid] = c;
    __syncthreads();
    for (int off = 1; off < SCAN_B; off <<= 1) {
        int t = (tid >= off) ? sm[tid - off] : 0;
        __syncthreads();
        sm[tid] += t;
        __syncthreads();
    }
    if (i < V_) offs[i] = pre[blockIdx.x] + sm[tid] - c;
}

// ---------------------------------------------------------------------------
// Scatter msgs into variable-major order (coalesced read, scattered 8B write)
__global__ void k_scatter_msgs(const int* __restrict__ edge_v,
                               const int* __restrict__ slot,
                               const int* __restrict__ offs,
                               const float2* __restrict__ msgs,
                               float2* __restrict__ srt) {
    int e = blockIdx.x * blockDim.x + threadIdx.x;
    if (e >= E_) return;
    srt[offs[edge_v[e]] + slot[e]] = msgs[e];
}

// ---------------------------------------------------------------------------
// Segment sum over variable-major srt -> clamped beliefs (used for prv & new)
__global__ void k_vb_seg(const int* __restrict__ offs,
                         const int* __restrict__ count,
                         const float2* __restrict__ srt,
                         const unsigned char* __restrict__ vb_mask,
                         float2* __restrict__ vb) {
    int v = blockIdx.x * blockDim.x + threadIdx.x;
    if (v >= V_) return;
    int o = offs[v], n = count[v];
    float s0 = 0.f, s1 = 0.f;
    for (int i = 0; i < n; ++i) {
        float2 m = srt[o + i];
        s0 += m.x; s1 += m.y;
    }
    float b0 = fmaxf(vb_mask[2 * v + 0] ? LN_ZERO : s0, LN_ZERO);
    float b1 = fmaxf(vb_mask[2 * v + 1] ? LN_ZERO : s1, LN_ZERO);
    vb[v] = make_float2(b0, b1);
}

// ---------------------------------------------------------------------------
// Per factor: v2f on the fly (vb gather, 2MB footprint -> L2), factor belief,
// max-marginalize, normalize -> out_f2v; also scatter into srt for vb_new.
__global__ void k_factor_msgs(const float2* __restrict__ msgs,
                              const int* __restrict__ edge_v,
                              const int* __restrict__ slot,
                              const int* __restrict__ offs,
                              const float2* __restrict__ vbP,     // clamped prv
                              const float4* __restrict__ pot4,
                              const int4* __restrict__ potmask4,
                              const unsigned char* __restrict__ f2v_mask,
                              const unsigned char* __restrict__ v2f_mask,
                              float2* __restrict__ out_f2v,
                              float2* __restrict__ srt) {
    int f = blockIdx.x * blockDim.x + threadIdx.x;
    if (f >= F_) return;

    float2 w[4];
    int rank[4];
#pragma unroll
    for (int d = 0; d < 4; ++d) {
        int e = 4 * f + d;
        int v = edge_v[e];
        float2 b = vbP[v];
        float2 m = msgs[e];
        float t0 = fmaxf(v2f_mask[2 * e + 0] ? LN_ZERO : (b.x - m.x), LN_ZERO);
        float t1 = fmaxf(v2f_mask[2 * e + 1] ? LN_ZERO : (b.y - m.y), LN_ZERO);
        w[d] = make_float2(t0, t1);
        rank[d] = offs[v] + slot[e];
    }

    float fb[16];
#pragma unroll
    for (int j = 0; j < 4; ++j) {
        float4 p = pot4[4 * f + j];
        int4 pm = potmask4[4 * f + j];
        float base[4] = {p.x, p.y, p.z, p.w};
        int   mb[4]   = {pm.x, pm.y, pm.z, pm.w};
#pragma unroll
        for (int k = 0; k < 4; ++k) {
            int s = 4 * j + k;
            float acc = base[k];
#pragma unroll
            for (int d = 0; d < 4; ++d) {
                int bit = (s >> (3 - d)) & 1;
                acc += bit ? w[d].y : w[d].x;
            }
            fb[s] = fmaxf(mb[k] == 1 ? LN_ZERO : acc, LN_ZERO);
        }
    }

    float mm[4][2];
#pragma unroll
    for (int d = 0; d < 4; ++d) { mm[d][0] = -INFINITY; mm[d][1] = -INFINITY; }
#pragma unroll
    for (int s = 0; s < 16; ++s) {
        float v = fb[s];
#pragma unroll
        for (int d = 0; d < 4; ++d) {
            int bit = (s >> (3 - d)) & 1;
            mm[d][bit] = fmaxf(mm[d][bit], v);
        }
    }

#pragma unroll
    for (int d = 0; d < 4; ++d) {
        int e = 4 * f + d;
        float raw0 = mm[d][0] - w[d].x;
        float raw1 = mm[d][1] - w[d].y;
        float mx = fmaxf(raw0, raw1);
        float lse = mx + logf(expf(raw0 - mx) + expf(raw1 - mx));
        float o0 = raw0 - lse;
        float o1 = raw1 - lse;
        o0 = fmaxf(f2v_mask[2 * e + 0] ? LN_ZERO : o0, LN_ZERO);
        o1 = fmaxf(f2v_mask[2 * e + 1] ? LN_ZERO : o1, LN_ZERO);
        float2 r = make_float2(o0, o1);
        out_f2v[e] = r;
        srt[rank[d]] = r;       // variable-major copy for the vb_new segment sum
    }
}

// ---------------------------------------------------------------------------
// Per factor: recompute v2f_new on the fly, fb_new = sum + pot (output)
__global__ void k_factor_beliefs(const float2* __restrict__ new_f2v,
                                 const float2* __restrict__ vb,      // clamped new
                                 const int* __restrict__ edge_v,
                                 const float4* __restrict__ pot4,
                                 const int4* __restrict__ potmask4,
                                 const unsigned char* __restrict__ v2f_mask,
                                 float4* __restrict__ out_fb4) {
    int f = blockIdx.x * blockDim.x + threadIdx.x;
    if (f >= F_) return;

    float2 w[4];
#pragma unroll
    for (int d = 0; d < 4; ++d) {
        int e = 4 * f + d;
        float2 b = vb[edge_v[e]];
        float2 g = new_f2v[e];
        float t0 = fmaxf(v2f_mask[2 * e + 0] ? LN_ZERO : (b.x - g.x), LN_ZERO);
        float t1 = fmaxf(v2f_mask[2 * e + 1] ? LN_ZERO : (b.y - g.y), LN_ZERO);
        w[d] = make_float2(t0, t1);
    }

#pragma unroll
    for (int j = 0; j < 4; ++j) {
        float4 p = pot4[4 * f + j];
        int4 pm = potmask4[4 * f + j];
        float base[4] = {p.x, p.y, p.z, p.w};
        int   mb[4]   = {pm.x, pm.y, pm.z, pm.w};
        float o[4];
#pragma unroll
        for (int k = 0; k < 4; ++k) {
            int s = 4 * j + k;
            float acc = base[k];
#pragma unroll
            for (int d = 0; d < 4; ++d) {
                int bit = (s >> (3 - d)) & 1;
                acc += bit ? w[d].y : w[d].x;
            }
            o[k] = fmaxf(mb[k] == 1 ? LN_ZERO : acc, LN_ZERO);
        }
        out_fb4[4 * f + j] = make_float4(o[0], o[1], o[2], o[3]);
    }
}

// ---------------------------------------------------------------------------
extern "C" void kernel_launch(void* const* d_in, const int* in_sizes, int n_in,
                              void* d_out, int out_size, void* d_ws, size_t ws_size,
                              hipStream_t stream) {
    const float* msgs     = (const float*)d_in[0];           // [E, C]
    const float* pot      = (const float*)d_in[1];           // [F, 16]
    const int*   edge_idx = (const int*)d_in[2];             // [2, E]
    const int*   pot_mask = (const int*)d_in[5];             // [F, 16] int32
    const unsigned char* f2v_mask = (const unsigned char*)d_in[6];  // [E, C]
    const unsigned char* v2f_mask = (const unsigned char*)d_in[7];  // [E, C]
    const unsigned char* vb_mask  = (const unsigned char*)d_in[8];  // [V, C]

    const int* edge_v = edge_idx + E_;

    float* out      = (float*)d_out;
    float* out_f2v  = out;                          // E*C floats
    float* out_vb   = out + (size_t)E_ * 2;         // V*C floats (also vb_prv tmp)
    float* out_fb   = out_vb + (size_t)V_ * 2;      // F*16 floats

    // workspace (ints): count[V] offs[V] slot[E] srt[2E] sums[256] pre[256]
    // total = 3.5M ints = 14,002,048 bytes
    int* ws_i  = (int*)d_ws;
    int* count = ws_i;                        // V
    int* offs  = ws_i + V_;                   // V
    int* slot  = ws_i + 2 * V_;               // E
    float2* srt = (float2*)(ws_i + 2 * V_ + E_);   // E float2
    int* sums  = ws_i + 2 * V_ + E_ + 2 * E_; // 256
    int* pre   = sums + 256;                  // 256

    hipMemsetAsync(count, 0, (size_t)V_ * sizeof(int), stream);

    const int B = 256;
    dim3 gE((E_ + B - 1) / B), gF((F_ + B - 1) / B), gV((V_ + B - 1) / B);

    k_slot<<<gE, B, 0, stream>>>(edge_v, count, slot);
    k_scan_blocksum<<<NB_SCAN, SCAN_B, 0, stream>>>(count, sums);
    k_scan_top<<<1, 256, 0, stream>>>(sums, pre);
    k_scan_offsets<<<NB_SCAN, SCAN_B, 0, stream>>>(count, pre, offs);

    // phase 1: scatter msgs -> variable-major, segment-sum -> vb_prv (in out_vb)
    k_scatter_msgs<<<gE, B, 0, stream>>>(edge_v, slot, offs, (const float2*)msgs, srt);
    k_vb_seg<<<gV, B, 0, stream>>>(offs, count, srt, vb_mask, (float2*)out_vb);

    // factor messages (fused v2f + scatter of new_f2v into srt)
    k_factor_msgs<<<gF, B, 0, stream>>>((const float2*)msgs, edge_v, slot, offs,
                                        (const float2*)out_vb,
                                        (const float4*)pot, (const int4*)pot_mask,
                                        f2v_mask, v2f_mask,
                                        (float2*)out_f2v, srt);

    // phase 2: vb_new (overwrites out_vb) and factor beliefs
    k_vb_seg<<<gV, B, 0, stream>>>(offs, count, srt, vb_mask, (float2*)out_vb);
    k_factor_beliefs<<<gF, B, 0, stream>>>((const float2*)out_f2v, (const float2*)out_vb,
                                           edge_v, (const float4*)pot,
                                           (const int4*)pot_mask, v2f_mask,
                                           (float4*)out_fb);
}

// Round 4
// 130.548 us; speedup vs baseline: 1.9191x; 1.0567x over previous
//
#include <hip/hip_runtime.h>
#include <math.h>

#define LN_ZERO (-100000000000.0f)

constexpr int F_ = 250000;
constexpr int V_ = 250000;
constexpr int E_ = 1000000;      // F_ * 4
constexpr int SCAN_B = 1024;
constexpr int NB_SCAN = (V_ + SCAN_B - 1) / SCAN_B;   // 245
static_assert(NB_SCAN <= 256, "top-level scan assumes <=256 partials");

// ---------------------------------------------------------------------------
// CSR build step 1: count[v]++ and remember each edge's slot within its var.
__global__ void k_slot(const int* __restrict__ edge_v,
                       int* __restrict__ count,
                       int* __restrict__ slot) {
    int e = blockIdx.x * blockDim.x + threadIdx.x;
    if (e >= E_) return;
    slot[e] = atomicAdd(&count[edge_v[e]], 1);
}

// CSR build step 2a: per-block sums of count
__global__ void k_scan_blocksum(const int* __restrict__ count,
                                int* __restrict__ sums) {
    __shared__ int sm[SCAN_B];
    int tid = threadIdx.x;
    int i = blockIdx.x * SCAN_B + tid;
    sm[tid] = (i < V_) ? count[i] : 0;
    __syncthreads();
    for (int s = SCAN_B / 2; s > 0; s >>= 1) {
        if (tid < s) sm[tid] += sm[tid + s];
        __syncthreads();
    }
    if (tid == 0) sums[blockIdx.x] = sm[0];
}

// CSR build step 2b: exclusive scan of the block sums (single block)
__global__ void k_scan_top(const int* __restrict__ sums,
                           int* __restrict__ pre) {
    __shared__ int sm[256];
    int tid = threadIdx.x;
    int v = (tid < NB_SCAN) ? sums[tid] : 0;
    sm[tid] = v;
    __syncthreads();
    for (int off = 1; off < 256; off <<= 1) {
        int t = (tid >= off) ? sm[tid - off] : 0;
        __syncthreads();
        sm[tid] += t;
        __syncthreads();
    }
    if (tid < NB_SCAN) pre[tid] = sm[tid] - v;   // exclusive prefix
}

// CSR build step 2c: offs[v] = global exclusive prefix of count
__global__ void k_scan_offsets(const int* __restrict__ count,
                               const int* __restrict__ pre,
                               int* __restrict__ offs) {
    __shared__ int sm[SCAN_B];
    int tid = threadIdx.x;
    int i = blockIdx.x * SCAN_B + tid;
    int c = (i < V_) ? count[i] : 0;
    sm[tid] = c;
    __syncthreads();
    for (int off = 1; off < SCAN_B; off <<= 1) {
        int t = (tid >= off) ? sm[tid - off] : 0;
        __syncthreads();
        sm[tid] += t;
        __syncthreads();
    }
    if (i < V_) offs[i] = pre[blockIdx.x] + sm[tid] - c;
}

// ---------------------------------------------------------------------------
// Scatter msgs into variable-major order AND finalize rank[e] in place of slot.
__global__ void k_scatter_rank(const int* __restrict__ edge_v,
                               int* __restrict__ slot_rank,   // in: slot, out: rank
                               const int* __restrict__ offs,
                               const float2* __restrict__ msgs,
                               float2* __restrict__ srt) {
    int e = blockIdx.x * blockDim.x + threadIdx.x;
    if (e >= E_) return;
    int r = offs[edge_v[e]] + slot_rank[e];
    slot_rank[e] = r;
    srt[r] = msgs[e];
}

// ---------------------------------------------------------------------------
// Segment sum over variable-major srt -> clamped beliefs (used for prv & new)
__global__ void k_vb_seg(const int* __restrict__ offs,
                         const int* __restrict__ count,
                         const float2* __restrict__ srt,
                         const unsigned char* __restrict__ vb_mask,
                         float2* __restrict__ vb) {
    int v = blockIdx.x * blockDim.x + threadIdx.x;
    if (v >= V_) return;
    int o = offs[v], n = count[v];
    float s0 = 0.f, s1 = 0.f;
    for (int i = 0; i < n; ++i) {
        float2 m = srt[o + i];
        s0 += m.x; s1 += m.y;
    }
    float b0 = fmaxf(vb_mask[2 * v + 0] ? LN_ZERO : s0, LN_ZERO);
    float b1 = fmaxf(vb_mask[2 * v + 1] ? LN_ZERO : s1, LN_ZERO);
    vb[v] = make_float2(b0, b1);
}

// ---------------------------------------------------------------------------
// Edge-parallel factor messages: 4 threads per factor (d = e & 3).
// Each thread computes its own v2f, exchanges via width-4 shuffles, computes
// its 4 factor states (s = 4d+k), butterfly max-marginalizes, normalizes,
// writes out_f2v[e] and scatters into srt[rank[e]] for the vb_new segment sum.
__global__ void k_factor_msgs(const float2* __restrict__ msgs,
                              const int* __restrict__ edge_v,
                              const int* __restrict__ rank,
                              const float2* __restrict__ vbP,     // clamped prv
                              const float4* __restrict__ pot4,
                              const int4* __restrict__ potmask4,
                              const unsigned short* __restrict__ f2v_mask2,
                              const unsigned short* __restrict__ v2f_mask2,
                              float2* __restrict__ out_f2v,
                              float2* __restrict__ srt) {
    int e = blockIdx.x * blockDim.x + threadIdx.x;
    if (e >= E_) return;
    int d = e & 3;

    float2 b = vbP[edge_v[e]];
    float2 m = msgs[e];
    unsigned short vm = v2f_mask2[e];
    float wx = fmaxf((vm & 0xff) ? LN_ZERO : (b.x - m.x), LN_ZERO);
    float wy = fmaxf((vm >> 8)   ? LN_ZERO : (b.y - m.y), LN_ZERO);

    // all four edges' v2f within the 4-lane group
    float w0x = __shfl(wx, 0, 4), w0y = __shfl(wy, 0, 4);
    float w1x = __shfl(wx, 1, 4), w1y = __shfl(wy, 1, 4);
    float w2x = __shfl(wx, 2, 4), w2y = __shfl(wy, 2, 4);
    float w3x = __shfl(wx, 3, 4), w3y = __shfl(wy, 3, 4);

    // this thread owns states s = 4d+k, k=0..3:
    // bit0(s)=d>>1, bit1(s)=d&1, bit2(s)=k>>1, bit3(s)=k&1
    float4 p = pot4[e];
    int4  pm = potmask4[e];
    float A = ((d >> 1) ? w0y : w0x) + ((d & 1) ? w1y : w1x);
    float fb0 = p.x + A + w2x + w3x;
    float fb1 = p.y + A + w2x + w3y;
    float fb2 = p.z + A + w2y + w3x;
    float fb3 = p.w + A + w2y + w3y;
    fb0 = fmaxf(pm.x == 1 ? LN_ZERO : fb0, LN_ZERO);
    fb1 = fmaxf(pm.y == 1 ? LN_ZERO : fb1, LN_ZERO);
    fb2 = fmaxf(pm.z == 1 ? LN_ZERO : fb2, LN_ZERO);
    fb3 = fmaxf(pm.w == 1 ? LN_ZERO : fb3, LN_ZERO);

    // per-thread partials split by k-bits, plus local total max
    float mk2_0 = fmaxf(fb0, fb1);   // bit2 == 0
    float mk2_1 = fmaxf(fb2, fb3);   // bit2 == 1
    float mk3_0 = fmaxf(fb0, fb2);   // bit3 == 0
    float mk3_1 = fmaxf(fb1, fb3);   // bit3 == 1
    float mloc  = fmaxf(mk2_0, mk2_1);

    // allreduce the k-bit partials over the 4-lane group
#pragma unroll
    for (int off = 1; off < 4; off <<= 1) {
        mk2_0 = fmaxf(mk2_0, __shfl_xor(mk2_0, off, 4));
        mk2_1 = fmaxf(mk2_1, __shfl_xor(mk2_1, off, 4));
        mk3_0 = fmaxf(mk3_0, __shfl_xor(mk3_0, off, 4));
        mk3_1 = fmaxf(mk3_1, __shfl_xor(mk3_1, off, 4));
    }
    // per-lane total maxes for the d-bit marginals
    float ml0 = __shfl(mloc, 0, 4);
    float ml1 = __shfl(mloc, 1, 4);
    float ml2 = __shfl(mloc, 2, 4);
    float ml3 = __shfl(mloc, 3, 4);

    float mm0, mm1;
    if (d == 0)      { mm0 = fmaxf(ml0, ml1); mm1 = fmaxf(ml2, ml3); }
    else if (d == 1) { mm0 = fmaxf(ml0, ml2); mm1 = fmaxf(ml1, ml3); }
    else if (d == 2) { mm0 = mk2_0;           mm1 = mk2_1; }
    else             { mm0 = mk3_0;           mm1 = mk3_1; }

    float raw0 = mm0 - wx;
    float raw1 = mm1 - wy;
    float mx = fmaxf(raw0, raw1);
    float lse = mx + logf(expf(raw0 - mx) + expf(raw1 - mx));
    unsigned short fm = f2v_mask2[e];
    float o0 = fmaxf((fm & 0xff) ? LN_ZERO : (raw0 - lse), LN_ZERO);
    float o1 = fmaxf((fm >> 8)   ? LN_ZERO : (raw1 - lse), LN_ZERO);
    float2 r = make_float2(o0, o1);
    out_f2v[e] = r;
    srt[rank[e]] = r;       // variable-major copy for the vb_new segment sum
}

// ---------------------------------------------------------------------------
// Edge-parallel factor beliefs: same 4-lane structure; each thread writes one
// coalesced float4 of the [F,16] output.
__global__ void k_factor_beliefs(const float2* __restrict__ new_f2v,
                                 const float2* __restrict__ vb,      // clamped new
                                 const int* __restrict__ edge_v,
                                 const float4* __restrict__ pot4,
                                 const int4* __restrict__ potmask4,
                                 const unsigned short* __restrict__ v2f_mask2,
                                 float4* __restrict__ out_fb4) {
    int e = blockIdx.x * blockDim.x + threadIdx.x;
    if (e >= E_) return;
    int d = e & 3;

    float2 b = vb[edge_v[e]];
    float2 g = new_f2v[e];
    unsigned short vm = v2f_mask2[e];
    float wx = fmaxf((vm & 0xff) ? LN_ZERO : (b.x - g.x), LN_ZERO);
    float wy = fmaxf((vm >> 8)   ? LN_ZERO : (b.y - g.y), LN_ZERO);

    float w0x = __shfl(wx, 0, 4), w0y = __shfl(wy, 0, 4);
    float w1x = __shfl(wx, 1, 4), w1y = __shfl(wy, 1, 4);
    float w2x = __shfl(wx, 2, 4), w2y = __shfl(wy, 2, 4);
    float w3x = __shfl(wx, 3, 4), w3y = __shfl(wy, 3, 4);

    float4 p = pot4[e];
    int4  pm = potmask4[e];
    float A = ((d >> 1) ? w0y : w0x) + ((d & 1) ? w1y : w1x);
    float o0 = fmaxf(pm.x == 1 ? LN_ZERO : (p.x + A + w2x + w3x), LN_ZERO);
    float o1 = fmaxf(pm.y == 1 ? LN_ZERO : (p.y + A + w2x + w3y), LN_ZERO);
    float o2 = fmaxf(pm.z == 1 ? LN_ZERO : (p.z + A + w2y + w3x), LN_ZERO);
    float o3 = fmaxf(pm.w == 1 ? LN_ZERO : (p.w + A + w2y + w3y), LN_ZERO);
    out_fb4[e] = make_float4(o0, o1, o2, o3);
}

// ---------------------------------------------------------------------------
extern "C" void kernel_launch(void* const* d_in, const int* in_sizes, int n_in,
                              void* d_out, int out_size, void* d_ws, size_t ws_size,
                              hipStream_t stream) {
    const float* msgs     = (const float*)d_in[0];           // [E, C]
    const float* pot      = (const float*)d_in[1];           // [F, 16]
    const int*   edge_idx = (const int*)d_in[2];             // [2, E]
    const int*   pot_mask = (const int*)d_in[5];             // [F, 16] int32
    const unsigned char* f2v_mask = (const unsigned char*)d_in[6];  // [E, C]
    const unsigned char* v2f_mask = (const unsigned char*)d_in[7];  // [E, C]
    const unsigned char* vb_mask  = (const unsigned char*)d_in[8];  // [V, C]

    const int* edge_v = edge_idx + E_;

    float* out      = (float*)d_out;
    float* out_f2v  = out;                          // E*C floats
    float* out_vb   = out + (size_t)E_ * 2;         // V*C floats (also vb_prv tmp)
    float* out_fb   = out_vb + (size_t)V_ * 2;      // F*16 floats

    // workspace (ints): count[V] offs[V] slot/rank[E] srt[2E] sums[256] pre[256]
    int* ws_i  = (int*)d_ws;
    int* count = ws_i;                        // V
    int* offs  = ws_i + V_;                   // V
    int* slot  = ws_i + 2 * V_;               // E (becomes rank after scatter)
    float2* srt = (float2*)(ws_i + 2 * V_ + E_);   // E float2
    int* sums  = ws_i + 2 * V_ + E_ + 2 * E_; // 256
    int* pre   = sums + 256;                  // 256

    hipMemsetAsync(count, 0, (size_t)V_ * sizeof(int), stream);

    const int B = 256;
    dim3 gE((E_ + B - 1) / B), gV((V_ + B - 1) / B);

    k_slot<<<gE, B, 0, stream>>>(edge_v, count, slot);
    k_scan_blocksum<<<NB_SCAN, SCAN_B, 0, stream>>>(count, sums);
    k_scan_top<<<1, 256, 0, stream>>>(sums, pre);
    k_scan_offsets<<<NB_SCAN, SCAN_B, 0, stream>>>(count, pre, offs);

    // phase 1: scatter msgs -> variable-major (+rank), segment-sum -> vb_prv
    k_scatter_rank<<<gE, B, 0, stream>>>(edge_v, slot, offs, (const float2*)msgs, srt);
    k_vb_seg<<<gV, B, 0, stream>>>(offs, count, srt, vb_mask, (float2*)out_vb);

    // factor messages (edge-parallel, fused v2f + scatter of new_f2v into srt)
    k_factor_msgs<<<gE, B, 0, stream>>>((const float2*)msgs, edge_v, slot,
                                        (const float2*)out_vb,
                                        (const float4*)pot, (const int4*)pot_mask,
                                        (const unsigned short*)f2v_mask,
                                        (const unsigned short*)v2f_mask,
                                        (float2*)out_f2v, srt);

    // phase 2: vb_new (overwrites out_vb) and factor beliefs
    k_vb_seg<<<gV, B, 0, stream>>>(offs, count, srt, vb_mask, (float2*)out_vb);
    k_factor_beliefs<<<gE, B, 0, stream>>>((const float2*)out_f2v, (const float2*)out_vb,
                                           edge_v, (const float4*)pot,
                                           (const int4*)pot_mask,
                                           (const unsigned short*)v2f_mask,
                                           (float4*)out_fb);
}

// Round 5
// 125.142 us; speedup vs baseline: 2.0020x; 1.0432x over previous
//
#include <hip/hip_runtime.h>
#include <hip/hip_fp16.h>
#include <math.h>

#define LN_ZERO (-100000000000.0f)

constexpr int F_ = 250000;
constexpr int V_ = 250000;
constexpr int E_ = 1000000;      // F_ * 4
constexpr int SCAN_B = 1024;
constexpr int NB_SCAN = (V_ + SCAN_B - 1) / SCAN_B;   // 245
static_assert(NB_SCAN <= 256, "top-level scan assumes <=256 partials");

// ---------------------------------------------------------------------------
// Prep: compress potmask [F,16] int32 -> ushort bitmask per factor; zero count.
__global__ void k_prep(const int4* __restrict__ potmask4,
                       unsigned short* __restrict__ potbits,
                       int* __restrict__ count) {
    int f = blockIdx.x * blockDim.x + threadIdx.x;
    if (f >= F_) return;
    unsigned int bits = 0;
#pragma unroll
    for (int j = 0; j < 4; ++j) {
        int4 pm = potmask4[4 * f + j];
        bits |= (pm.x == 1 ? 1u : 0u) << (4 * j + 0);
        bits |= (pm.y == 1 ? 1u : 0u) << (4 * j + 1);
        bits |= (pm.z == 1 ? 1u : 0u) << (4 * j + 2);
        bits |= (pm.w == 1 ? 1u : 0u) << (4 * j + 3);
    }
    potbits[f] = (unsigned short)bits;
    count[f] = 0;    // F_ == V_
}

// ---------------------------------------------------------------------------
// CSR build step 1: count[v]++ and remember each edge's slot within its var.
__global__ void k_slot(const int* __restrict__ edge_v,
                       int* __restrict__ count,
                       int* __restrict__ slot) {
    int e = blockIdx.x * blockDim.x + threadIdx.x;
    if (e >= E_) return;
    slot[e] = atomicAdd(&count[edge_v[e]], 1);
}

// CSR build step 2a: per-block sums of count
__global__ void k_scan_blocksum(const int* __restrict__ count,
                                int* __restrict__ sums) {
    __shared__ int sm[SCAN_B];
    int tid = threadIdx.x;
    int i = blockIdx.x * SCAN_B + tid;
    sm[tid] = (i < V_) ? count[i] : 0;
    __syncthreads();
    for (int s = SCAN_B / 2; s > 0; s >>= 1) {
        if (tid < s) sm[tid] += sm[tid + s];
        __syncthreads();
    }
    if (tid == 0) sums[blockIdx.x] = sm[0];
}

// CSR build step 2b: exclusive scan of the block sums (single block)
__global__ void k_scan_top(const int* __restrict__ sums,
                           int* __restrict__ pre) {
    __shared__ int sm[256];
    int tid = threadIdx.x;
    int v = (tid < NB_SCAN) ? sums[tid] : 0;
    sm[tid] = v;
    __syncthreads();
    for (int off = 1; off < 256; off <<= 1) {
        int t = (tid >= off) ? sm[tid - off] : 0;
        __syncthreads();
        sm[tid] += t;
        __syncthreads();
    }
    if (tid < NB_SCAN) pre[tid] = sm[tid] - v;   // exclusive prefix
}

// CSR build step 2c: offs[v] = global exclusive prefix of count
__global__ void k_scan_offsets(const int* __restrict__ count,
                               const int* __restrict__ pre,
                               int* __restrict__ offs) {
    __shared__ int sm[SCAN_B];
    int tid = threadIdx.x;
    int i = blockIdx.x * SCAN_B + tid;
    int c = (i < V_) ? count[i] : 0;
    sm[tid] = c;
    __syncthreads();
    for (int off = 1; off < SCAN_B; off <<= 1) {
        int t = (tid >= off) ? sm[tid - off] : 0;
        __syncthreads();
        sm[tid] += t;
        __syncthreads();
    }
    if (i < V_) offs[i] = pre[blockIdx.x] + sm[tid] - c;
}

// ---------------------------------------------------------------------------
// Scatter msgs (as half2) into variable-major order; finalize rank[e] in place.
__global__ void k_scatter_rank(const int* __restrict__ edge_v,
                               int* __restrict__ slot_rank,   // in: slot, out: rank
                               const int* __restrict__ offs,
                               const float2* __restrict__ msgs,
                               __half2* __restrict__ srt) {
    int e = blockIdx.x * blockDim.x + threadIdx.x;
    if (e >= E_) return;
    int r = offs[edge_v[e]] + slot_rank[e];
    slot_rank[e] = r;
    float2 m = msgs[e];
    srt[r] = __floats2half2_rn(m.x, m.y);
}

// ---------------------------------------------------------------------------
// Segment sum over variable-major srt (half2) -> clamped beliefs (f32)
__global__ void k_vb_seg(const int* __restrict__ offs,
                         const int* __restrict__ count,
                         const __half2* __restrict__ srt,
                         const unsigned char* __restrict__ vb_mask,
                         float2* __restrict__ vb) {
    int v = blockIdx.x * blockDim.x + threadIdx.x;
    if (v >= V_) return;
    int o = offs[v], n = count[v];
    float s0 = 0.f, s1 = 0.f;
    for (int i = 0; i < n; ++i) {
        float2 m = __half22float2(srt[o + i]);
        s0 += m.x; s1 += m.y;
    }
    float b0 = fmaxf(vb_mask[2 * v + 0] ? LN_ZERO : s0, LN_ZERO);
    float b1 = fmaxf(vb_mask[2 * v + 1] ? LN_ZERO : s1, LN_ZERO);
    vb[v] = make_float2(b0, b1);
}

// ---------------------------------------------------------------------------
// Edge-parallel factor messages: 4 threads per factor (d = e & 3).
__global__ void k_factor_msgs(const float2* __restrict__ msgs,
                              const int* __restrict__ edge_v,
                              const int* __restrict__ rank,
                              const float2* __restrict__ vbP,     // clamped prv
                              const float4* __restrict__ pot4,
                              const unsigned short* __restrict__ potbits,
                              const unsigned short* __restrict__ f2v_mask2,
                              const unsigned short* __restrict__ v2f_mask2,
                              float2* __restrict__ out_f2v,
                              __half2* __restrict__ srt) {
    int e = blockIdx.x * blockDim.x + threadIdx.x;
    if (e >= E_) return;
    int d = e & 3;

    float2 b = vbP[edge_v[e]];
    float2 m = msgs[e];
    unsigned short vm = v2f_mask2[e];
    float wx = fmaxf((vm & 0xff) ? LN_ZERO : (b.x - m.x), LN_ZERO);
    float wy = fmaxf((vm >> 8)   ? LN_ZERO : (b.y - m.y), LN_ZERO);

    // all four edges' v2f within the 4-lane group
    float w0x = __shfl(wx, 0, 4), w0y = __shfl(wy, 0, 4);
    float w1x = __shfl(wx, 1, 4), w1y = __shfl(wy, 1, 4);
    float w2x = __shfl(wx, 2, 4), w2y = __shfl(wy, 2, 4);
    float w3x = __shfl(wx, 3, 4), w3y = __shfl(wy, 3, 4);

    // this thread owns states s = 4d+k, k=0..3:
    // bit0(s)=d>>1, bit1(s)=d&1, bit2(s)=k>>1, bit3(s)=k&1
    float4 p = pot4[e];
    unsigned int pb = potbits[e >> 2] >> (4 * d);   // nibble for k=0..3
    float A = ((d >> 1) ? w0y : w0x) + ((d & 1) ? w1y : w1x);
    float fb0 = p.x + A + w2x + w3x;
    float fb1 = p.y + A + w2x + w3y;
    float fb2 = p.z + A + w2y + w3x;
    float fb3 = p.w + A + w2y + w3y;
    fb0 = fmaxf((pb & 1u) ? LN_ZERO : fb0, LN_ZERO);
    fb1 = fmaxf((pb & 2u) ? LN_ZERO : fb1, LN_ZERO);
    fb2 = fmaxf((pb & 4u) ? LN_ZERO : fb2, LN_ZERO);
    fb3 = fmaxf((pb & 8u) ? LN_ZERO : fb3, LN_ZERO);

    // per-thread partials split by k-bits, plus local total max
    float mk2_0 = fmaxf(fb0, fb1);   // bit2 == 0
    float mk2_1 = fmaxf(fb2, fb3);   // bit2 == 1
    float mk3_0 = fmaxf(fb0, fb2);   // bit3 == 0
    float mk3_1 = fmaxf(fb1, fb3);   // bit3 == 1
    float mloc  = fmaxf(mk2_0, mk2_1);

#pragma unroll
    for (int off = 1; off < 4; off <<= 1) {
        mk2_0 = fmaxf(mk2_0, __shfl_xor(mk2_0, off, 4));
        mk2_1 = fmaxf(mk2_1, __shfl_xor(mk2_1, off, 4));
        mk3_0 = fmaxf(mk3_0, __shfl_xor(mk3_0, off, 4));
        mk3_1 = fmaxf(mk3_1, __shfl_xor(mk3_1, off, 4));
    }
    float ml0 = __shfl(mloc, 0, 4);
    float ml1 = __shfl(mloc, 1, 4);
    float ml2 = __shfl(mloc, 2, 4);
    float ml3 = __shfl(mloc, 3, 4);

    float mm0, mm1;
    if (d == 0)      { mm0 = fmaxf(ml0, ml1); mm1 = fmaxf(ml2, ml3); }
    else if (d == 1) { mm0 = fmaxf(ml0, ml2); mm1 = fmaxf(ml1, ml3); }
    else if (d == 2) { mm0 = mk2_0;           mm1 = mk2_1; }
    else             { mm0 = mk3_0;           mm1 = mk3_1; }

    float raw0 = mm0 - wx;
    float raw1 = mm1 - wy;
    float mx = fmaxf(raw0, raw1);
    float lse = mx + logf(expf(raw0 - mx) + expf(raw1 - mx));
    unsigned short fm = f2v_mask2[e];
    float o0 = fmaxf((fm & 0xff) ? LN_ZERO : (raw0 - lse), LN_ZERO);
    float o1 = fmaxf((fm >> 8)   ? LN_ZERO : (raw1 - lse), LN_ZERO);
    out_f2v[e] = make_float2(o0, o1);
    srt[rank[e]] = __floats2half2_rn(o0, o1);   // variable-major copy for vb_new
}

// ---------------------------------------------------------------------------
// Edge-parallel factor beliefs: each thread writes one float4 of [F,16].
__global__ void k_factor_beliefs(const float2* __restrict__ new_f2v,
                                 const float2* __restrict__ vb,      // clamped new
                                 const int* __restrict__ edge_v,
                                 const float4* __restrict__ pot4,
                                 const unsigned short* __restrict__ potbits,
                                 const unsigned short* __restrict__ v2f_mask2,
                                 float4* __restrict__ out_fb4) {
    int e = blockIdx.x * blockDim.x + threadIdx.x;
    if (e >= E_) return;
    int d = e & 3;

    float2 b = vb[edge_v[e]];
    float2 g = new_f2v[e];
    unsigned short vm = v2f_mask2[e];
    float wx = fmaxf((vm & 0xff) ? LN_ZERO : (b.x - g.x), LN_ZERO);
    float wy = fmaxf((vm >> 8)   ? LN_ZERO : (b.y - g.y), LN_ZERO);

    float w0x = __shfl(wx, 0, 4), w0y = __shfl(wy, 0, 4);
    float w1x = __shfl(wx, 1, 4), w1y = __shfl(wy, 1, 4);
    float w2x = __shfl(wx, 2, 4), w2y = __shfl(wy, 2, 4);
    float w3x = __shfl(wx, 3, 4), w3y = __shfl(wy, 3, 4);

    float4 p = pot4[e];
    unsigned int pb = potbits[e >> 2] >> (4 * d);
    float A = ((d >> 1) ? w0y : w0x) + ((d & 1) ? w1y : w1x);
    float o0 = fmaxf((pb & 1u) ? LN_ZERO : (p.x + A + w2x + w3x), LN_ZERO);
    float o1 = fmaxf((pb & 2u) ? LN_ZERO : (p.y + A + w2x + w3y), LN_ZERO);
    float o2 = fmaxf((pb & 4u) ? LN_ZERO : (p.z + A + w2y + w3x), LN_ZERO);
    float o3 = fmaxf((pb & 8u) ? LN_ZERO : (p.w + A + w2y + w3y), LN_ZERO);
    out_fb4[e] = make_float4(o0, o1, o2, o3);
}

// ---------------------------------------------------------------------------
extern "C" void kernel_launch(void* const* d_in, const int* in_sizes, int n_in,
                              void* d_out, int out_size, void* d_ws, size_t ws_size,
                              hipStream_t stream) {
    const float* msgs     = (const float*)d_in[0];           // [E, C]
    const float* pot      = (const float*)d_in[1];           // [F, 16]
    const int*   edge_idx = (const int*)d_in[2];             // [2, E]
    const int*   pot_mask = (const int*)d_in[5];             // [F, 16] int32
    const unsigned char* f2v_mask = (const unsigned char*)d_in[6];  // [E, C]
    const unsigned char* v2f_mask = (const unsigned char*)d_in[7];  // [E, C]
    const unsigned char* vb_mask  = (const unsigned char*)d_in[8];  // [V, C]

    const int* edge_v = edge_idx + E_;

    float* out      = (float*)d_out;
    float* out_f2v  = out;                          // E*C floats
    float* out_vb   = out + (size_t)E_ * 2;         // V*C floats (also vb_prv tmp)
    float* out_fb   = out_vb + (size_t)V_ * 2;      // F*16 floats

    // workspace (ints): count[V] offs[V] slot/rank[E] srt(half2[E]=E ints)
    //                   potbits(ushort[F]=F/2 ints) sums[256] pre[256]
    int* ws_i  = (int*)d_ws;
    int* count = ws_i;                            // V
    int* offs  = ws_i + V_;                       // V
    int* slot  = ws_i + 2 * V_;                   // E (becomes rank)
    __half2* srt = (__half2*)(ws_i + 2 * V_ + E_);          // E half2 = E ints
    unsigned short* potbits = (unsigned short*)(ws_i + 2 * V_ + 2 * E_);  // F/2 ints
    int* sums  = ws_i + 2 * V_ + 2 * E_ + F_ / 2; // 256
    int* pre   = sums + 256;                      // 256
    // total ints: 2V + 2E + F/2 + 512 = 3,125,512 (~12.5 MB)

    const int B = 256;
    dim3 gE((E_ + B - 1) / B), gF((F_ + B - 1) / B), gV((V_ + B - 1) / B);

    k_prep<<<gF, B, 0, stream>>>((const int4*)pot_mask, potbits, count);
    k_slot<<<gE, B, 0, stream>>>(edge_v, count, slot);
    k_scan_blocksum<<<NB_SCAN, SCAN_B, 0, stream>>>(count, sums);
    k_scan_top<<<1, 256, 0, stream>>>(sums, pre);
    k_scan_offsets<<<NB_SCAN, SCAN_B, 0, stream>>>(count, pre, offs);

    // phase 1: scatter msgs -> variable-major (+rank), segment-sum -> vb_prv
    k_scatter_rank<<<gE, B, 0, stream>>>(edge_v, slot, offs, (const float2*)msgs, srt);
    k_vb_seg<<<gV, B, 0, stream>>>(offs, count, srt, vb_mask, (float2*)out_vb);

    // factor messages (edge-parallel, fused v2f + scatter of new_f2v into srt)
    k_factor_msgs<<<gE, B, 0, stream>>>((const float2*)msgs, edge_v, slot,
                                        (const float2*)out_vb,
                                        (const float4*)pot, potbits,
                                        (const unsigned short*)f2v_mask,
                                        (const unsigned short*)v2f_mask,
                                        (float2*)out_f2v, srt);

    // phase 2: vb_new (overwrites out_vb) and factor beliefs
    k_vb_seg<<<gV, B, 0, stream>>>(offs, count, srt, vb_mask, (float2*)out_vb);
    k_factor_beliefs<<<gE, B, 0, stream>>>((const float2*)out_f2v, (const float2*)out_vb,
                                           edge_v, (const float4*)pot, potbits,
                                           (const unsigned short*)v2f_mask,
                                           (float4*)out_fb);
}